// Round 4
// baseline (277.783 us; speedup 1.0000x reference)
//
#include <hip/hip_runtime.h>
#include <hip/hip_bf16.h>
#include <math.h>

// Problem constants (fixed by setup_inputs)
#define M_TOT 2
#define N_TOT 4096
#define DZ    64
#define G_TOT 16384

// R3 post-mortem: the R1-R3 "atomic pathology" was really REGISTER SPILL.
// __launch_bounds__(512,8) caps VGPR at 64; the 512T kernel needed ~100+,
// spilled accumulators to scratch -> 300-400MB of HBM scratch traffic
// (VGPR_Count=32 was the tell; R0 uses 52). Atomics were always clean:
// R0's WRITE = exactly NSPLIT*8MB, FETCH 12.7MB (L2/L3-resolved RMW;
// R2's swizzle-null confirms placement-independence).
// Fix: keep the proven R0 block (256T, 4 waves, 32 g-rows/wave, VGPR 52)
// EXACTLY, and raise occupancy with the GRID: NSPLIT=8 -> 2048 blocks
// = 8 blocks/CU x 4 waves = 32 waves/CU. LDS 17.9KB x 8 = 143KB <= 160KB.
// launch_bounds(256,8): VGPR cap 64 >= 52 actually needed -> no spill.
#define BG      128
#define BN      64
#define THREADS 256
#define NSPLIT  8
#define NCHUNK  (N_TOT / NSPLIT)   // 512
#define ITERS   (NCHUNK / BN)      // 8
// zT: bf16 [dz=64][n=64], row = 128 B. Full 3-bit XOR swizzle of the 16B block:
// phys_block = logical_block ^ ((row>>1)&7). Proven conflict-free for both the
// b64 staging writes (4 dwords/bank = b64 floor) and the b128 B-frag reads
// (8 dwords/bank = b128 floor). k-order inside 16B blocks preserved.
#define ZROW_B  128
#define ZT_B    (DZ * ZROW_B)      // 8192
#define KX_OFS  ZT_B               // 8192
#define KY_OFS  (KX_OFS + BN * 4)  // 8448
#define HK_OFS  (KY_OFS + BN * 4)  // 8704
#define BUF_B   (HK_OFS + BN * 4)  // 8960 bytes per pipeline buffer

typedef __attribute__((ext_vector_type(8))) short short8;  // 8 bf16 MFMA A/B frag
typedef __attribute__((ext_vector_type(4))) float f32x4;   // MFMA C/D frag
typedef __attribute__((ext_vector_type(4))) int   int4v;

#if __has_builtin(__builtin_amdgcn_cvt_pk_bf16_f32)
typedef __attribute__((ext_vector_type(2))) __bf16 bf16x2;
__device__ __forceinline__ unsigned int pack_bf16_pair(float lo, float hi) {
    return __builtin_bit_cast(unsigned int, __builtin_amdgcn_cvt_pk_bf16_f32(lo, hi));
}
#else
__device__ __forceinline__ unsigned int pack_bf16_pair(float lo, float hi) {
    const unsigned int a = __float_as_uint(lo) + 0x8000u;  // round-half-up to bf16
    const unsigned int b = __float_as_uint(hi) + 0x8000u;
    return __builtin_amdgcn_perm(b, a, 0x07060302u);       // [lo[31:16], hi[31:16]]
}
#endif

__global__ __launch_bounds__(THREADS, 8)  // 8 blocks/CU -> 32 waves/CU; VGPR cap 64 (need 52)
void setconv_kernel(const float* __restrict__ x,       // [2][4096][2]
                    const float* __restrict__ z,       // [2][4096][64]
                    const float* __restrict__ x_grid,  // [2][16384][2]
                    const float* __restrict__ z_grid,  // [2][16384][64]
                    const float* __restrict__ lsp,     // [2]
                    float* __restrict__ out)           // [2][16384][64], memset to 0
{
    __shared__ __align__(16) unsigned char lds[2 * BUF_B];

    const int tid  = threadIdx.x;
    const int wave = tid >> 6;
    const int lane = tid & 63;
    const int quad = lane >> 4;
    const int l16  = lane & 15;

    const int mb    = blockIdx.y;
    const int gbase = blockIdx.x * BG;
    const int nbase = blockIdx.z * NCHUNK;

    const float LOG2E = 1.44269504088896340736f;
    const float inv0 = 1.0f / (1e-5f + log1pf(__expf(lsp[0])));
    const float inv1 = 1.0f / (1e-5f + log1pf(__expf(lsp[1])));

    // Two row-groups per wave: rows wave*32 + {l16, 16+l16}.
    float qxL[2], qyL[2], hq[2];
#pragma unroll
    for (int g = 0; g < 2; g++) {
        const int grow = gbase + wave * 32 + g * 16 + l16;
        const float2 qraw = *(const float2*)&x_grid[(size_t)(mb * G_TOT + grow) * 2];
        const float qx = qraw.x * inv0, qy = qraw.y * inv1;
        qxL[g] = LOG2E * qx;
        qyL[g] = LOG2E * qy;
        hq[g]  = -0.5f * LOG2E * (qx * qx + qy * qy);
    }

    // Staging: sdzg = dz-group (consecutive lanes -> consecutive dz -> coalesced
    // float4 global loads), snq = n-quad (n = snq*4 + j).
    const int sdzg = tid & 15;
    const int snq  = tid >> 4;
    const float* zb = z + (size_t)mb * N_TOT * DZ + sdzg * 4;
    // Swizzled write bases (loop-invariant). Row d = sdzg*4 + i; swz(d) = (d>>1)&7
    // = (sdzg&3)*2 + (i>>1). Logical block = snq>>1, sub-offset = (snq&1)*8.
    const unsigned wrow  = (unsigned)(sdzg * 4) * ZROW_B + (unsigned)(snq & 1) * 8;
    const unsigned wb_lo = (unsigned)(((snq >> 1) ^ ((sdzg & 3) * 2 + 0)) & 7) * 16;  // i = 0,1
    const unsigned wb_hi = (unsigned)(((snq >> 1) ^ ((sdzg & 3) * 2 + 1)) & 7) * 16;  // i = 2,3

    // Swizzled read bases: row r = nt*16 + l16 -> swz = (l16>>1)&7 (nt*8 ≡ 0 mod 8);
    // block b = kc*4 + quad -> phys = (quad ^ swz) ^ (kc*4).
    const unsigned swz_l = (unsigned)((l16 >> 1) & 7);
    const unsigned q0    = (unsigned)quad ^ swz_l;
    const unsigned rbA   = (unsigned)l16 * ZROW_B + q0 * 16;         // kc = 0
    const unsigned rbB   = (unsigned)l16 * ZROW_B + (q0 ^ 4u) * 16;  // kc = 1

    f32x4 acc[2][4];
#pragma unroll
    for (int g = 0; g < 2; g++)
#pragma unroll
        for (int i = 0; i < 4; i++) acc[g][i] = (f32x4){0.f, 0.f, 0.f, 0.f};

    auto stage = [&](unsigned dst, const float4* zf, float2 kraw) {
        const float a0[4] = {zf[0].x, zf[0].y, zf[0].z, zf[0].w};
        const float a1[4] = {zf[1].x, zf[1].y, zf[1].z, zf[1].w};
        const float a2[4] = {zf[2].x, zf[2].y, zf[2].z, zf[2].w};
        const float a3[4] = {zf[3].x, zf[3].y, zf[3].z, zf[3].w};
#pragma unroll
        for (int i = 0; i < 4; i++) {
            uint2 w;
            w.x = pack_bf16_pair(a0[i], a1[i]);
            w.y = pack_bf16_pair(a2[i], a3[i]);
            const unsigned base = (i < 2) ? wb_lo : wb_hi;
            *(uint2*)(lds + dst + wrow + i * ZROW_B + base) = w;
        }
        if (tid < BN) {
            const float kx = kraw.x * inv0, ky = kraw.y * inv1;
            *(float*)(lds + dst + KX_OFS + tid * 4) = kx;
            *(float*)(lds + dst + KY_OFS + tid * 4) = ky;
            *(float*)(lds + dst + HK_OFS + tid * 4) = -0.5f * LOG2E * (kx * kx + ky * ky);
        }
    };

    // ---- prologue: fetch + stage tile 0 into buffer 0 ----
    {
        float4 zf[4];
        float2 kraw = {0.f, 0.f};
        const float* zp = zb + (size_t)(nbase + snq * 4) * DZ;
#pragma unroll
        for (int j = 0; j < 4; j++) zf[j] = *(const float4*)(zp + j * DZ);
        if (tid < BN) kraw = *(const float2*)(x + (size_t)(mb * N_TOT + nbase + tid) * 2);
        stage(0u, zf, kraw);
    }
    __syncthreads();

    for (int t = 0; t < ITERS; t++) {
        const unsigned bo = (unsigned)((t & 1) ? BUF_B : 0);
        const unsigned bn = bo ^ (unsigned)BUF_B;

        // ---- issue next tile's global loads (latency hidden under compute) ----
        float4 zf[4];
        float2 kraw = {0.f, 0.f};
        if (t + 1 < ITERS) {
            const int nb1 = nbase + (t + 1) * BN;
            const float* zp = zb + (size_t)(nb1 + snq * 4) * DZ;
#pragma unroll
            for (int j = 0; j < 4; j++) zf[j] = *(const float4*)(zp + j * DZ);
            if (tid < BN) kraw = *(const float2*)(x + (size_t)(mb * N_TOT + nb1 + tid) * 2);
        }

        // ---- compute tile t from buffer bo ----
#pragma unroll
        for (int kc = 0; kc < 2; kc++) {
            const unsigned kb = bo + (unsigned)(kc * 128 + quad * 32);
            const float4 kxa = *(const float4*)(lds + kb + KX_OFS);
            const float4 kxb = *(const float4*)(lds + kb + KX_OFS + 16);
            const float4 kya = *(const float4*)(lds + kb + KY_OFS);
            const float4 kyb = *(const float4*)(lds + kb + KY_OFS + 16);
            const float4 hka = *(const float4*)(lds + kb + HK_OFS);
            const float4 hkb = *(const float4*)(lds + kb + HK_OFS + 16);
            const float kxr[8] = {kxa.x, kxa.y, kxa.z, kxa.w, kxb.x, kxb.y, kxb.z, kxb.w};
            const float kyr[8] = {kya.x, kya.y, kya.z, kya.w, kyb.x, kyb.y, kyb.z, kyb.w};
            const float hkr[8] = {hka.x, hka.y, hka.z, hka.w, hkb.x, hkb.y, hkb.z, hkb.w};

            // Weights for both row-groups, directly in A-frag layout.
            unsigned aw[2][4];
#pragma unroll
            for (int jp = 0; jp < 4; jp++) {
#pragma unroll
                for (int g = 0; g < 2; g++) {
                    const float s0 = fmaf(qxL[g], kxr[2 * jp],
                                      fmaf(qyL[g], kyr[2 * jp], hq[g] + hkr[2 * jp]));
                    const float s1 = fmaf(qxL[g], kxr[2 * jp + 1],
                                      fmaf(qyL[g], kyr[2 * jp + 1], hq[g] + hkr[2 * jp + 1]));
                    aw[g][jp] = pack_bf16_pair(__builtin_amdgcn_exp2f(s0),
                                               __builtin_amdgcn_exp2f(s1));
                }
            }
            const int4v  a0v = {(int)aw[0][0], (int)aw[0][1], (int)aw[0][2], (int)aw[0][3]};
            const int4v  a1v = {(int)aw[1][0], (int)aw[1][1], (int)aw[1][2], (int)aw[1][3]};
            const short8 af0 = __builtin_bit_cast(short8, a0v);
            const short8 af1 = __builtin_bit_cast(short8, a1v);

            // B-frags (shared by both row-groups) + 8 MFMA.
            const unsigned rb = bo + ((kc == 0) ? rbA : rbB);
#pragma unroll
            for (int nt = 0; nt < 4; nt++) {
                const short8 bfrag = *(const short8*)(lds + rb + nt * (16 * ZROW_B));
                acc[0][nt] = __builtin_amdgcn_mfma_f32_16x16x32_bf16(af0, bfrag, acc[0][nt], 0, 0, 0);
                acc[1][nt] = __builtin_amdgcn_mfma_f32_16x16x32_bf16(af1, bfrag, acc[1][nt], 0, 0, 0);
            }
        }

        // ---- stage next tile into buffer bn; single barrier per iteration ----
        if (t + 1 < ITERS) {
            stage(bn, zf, kraw);
            __syncthreads();
        }
    }

    // ---- epilogue: C/D layout col = lane&15 (dz), row = quad*4 + reg (g-row) ----
    // out was memset to 0; all 8 n-splits atomicAdd (RMW resolves at shared
    // cache level -- R0-proven clean, placement-independent). Split 0 folds
    // z_grid in.
    const bool add_zg = (blockIdx.z == 0);
#pragma unroll
    for (int g = 0; g < 2; g++) {
        const int gout = gbase + wave * 32 + g * 16 + quad * 4;
#pragma unroll
        for (int nt = 0; nt < 4; nt++) {
#pragma unroll
            for (int r = 0; r < 4; r++) {
                const size_t idx = (size_t)(mb * G_TOT + gout + r) * DZ + nt * 16 + l16;
                const float v = add_zg ? (acc[g][nt][r] + z_grid[idx]) : acc[g][nt][r];
                atomicAdd(&out[idx], v);
            }
        }
    }
}

extern "C" void kernel_launch(void* const* d_in, const int* in_sizes, int n_in,
                              void* d_out, int out_size, void* d_ws, size_t ws_size,
                              hipStream_t stream) {
    const float* x   = (const float*)d_in[0];
    const float* z   = (const float*)d_in[1];
    const float* xg  = (const float*)d_in[2];
    const float* zgr = (const float*)d_in[3];
    const float* lsp = (const float*)d_in[4];
    float* out = (float*)d_out;

    // out = 0 (write-only memset node; z_grid folded in by split 0's atomics)
    hipMemsetAsync(out, 0, sizeof(float) * (size_t)M_TOT * G_TOT * DZ, stream);

    dim3 grid(G_TOT / BG, M_TOT, NSPLIT);   // (128, 2, 8) = 2048 blocks
    setconv_kernel<<<grid, THREADS, 0, stream>>>(x, z, xg, zgr, lsp, out);
}

// Round 5
// 136.112 us; speedup vs baseline: 2.0409x; 2.0409x over previous
//
#include <hip/hip_runtime.h>
#include <hip/hip_bf16.h>
#include <math.h>

// Problem constants (fixed by setup_inputs)
#define M_TOT 2
#define N_TOT 4096
#define DZ    64
#define G_TOT 16384

// R4 post-mortem (the R1-R4 unifying cause): __launch_bounds__(...,8) caps
// the UNIFIED VGPR+acc file at 64 regs; compiler reserves 32 for the 8 f32x4
// MFMA accumulators, leaving 32 arch VGPRs (VGPR_Count=32 in every spilled
// round) -> guaranteed scratch spill -> 200-600MB of HBM scratch traffic.
// Atomics and NSPLIT were never the problem. R0's (256,4) bound = cap 128,
// natural alloc 52, zero scratch.
// This round: R0's exact block config + (256,4) bound; occupancy raised via
// GRID only: NSPLIT=8 -> 2048 blocks. HW residency: ~84 total regs ->
// 6 waves/SIMD -> 6 blocks/CU = 24 waves/CU (R0 grid-capped at 4 blocks=16).
// LDS 17.9KB x 6 = 105KB <= 160KB.
#define BG      128
#define BN      64
#define THREADS 256
#define NSPLIT  8
#define NCHUNK  (N_TOT / NSPLIT)   // 512
#define ITERS   (NCHUNK / BN)      // 8
// zT: bf16 [dz=64][n=64], row = 128 B. Full 3-bit XOR swizzle of the 16B block:
// phys_block = logical_block ^ ((row>>1)&7). Proven conflict-free for both the
// b64 staging writes (4 dwords/bank = b64 floor) and the b128 B-frag reads
// (8 dwords/bank = b128 floor). k-order inside 16B blocks preserved.
#define ZROW_B  128
#define ZT_B    (DZ * ZROW_B)      // 8192
#define KX_OFS  ZT_B               // 8192
#define KY_OFS  (KX_OFS + BN * 4)  // 8448
#define HK_OFS  (KY_OFS + BN * 4)  // 8704
#define BUF_B   (HK_OFS + BN * 4)  // 8960 bytes per pipeline buffer

typedef __attribute__((ext_vector_type(8))) short short8;  // 8 bf16 MFMA A/B frag
typedef __attribute__((ext_vector_type(4))) float f32x4;   // MFMA C/D frag
typedef __attribute__((ext_vector_type(4))) int   int4v;

#if __has_builtin(__builtin_amdgcn_cvt_pk_bf16_f32)
typedef __attribute__((ext_vector_type(2))) __bf16 bf16x2;
__device__ __forceinline__ unsigned int pack_bf16_pair(float lo, float hi) {
    return __builtin_bit_cast(unsigned int, __builtin_amdgcn_cvt_pk_bf16_f32(lo, hi));
}
#else
__device__ __forceinline__ unsigned int pack_bf16_pair(float lo, float hi) {
    const unsigned int a = __float_as_uint(lo) + 0x8000u;  // round-half-up to bf16
    const unsigned int b = __float_as_uint(hi) + 0x8000u;
    return __builtin_amdgcn_perm(b, a, 0x07060302u);       // [lo[31:16], hi[31:16]]
}
#endif

__global__ __launch_bounds__(THREADS, 4)  // cap 128 regs: known-good (R0, no spill)
void setconv_kernel(const float* __restrict__ x,       // [2][4096][2]
                    const float* __restrict__ z,       // [2][4096][64]
                    const float* __restrict__ x_grid,  // [2][16384][2]
                    const float* __restrict__ z_grid,  // [2][16384][64]
                    const float* __restrict__ lsp,     // [2]
                    float* __restrict__ out)           // [2][16384][64], memset to 0
{
    __shared__ __align__(16) unsigned char lds[2 * BUF_B];

    const int tid  = threadIdx.x;
    const int wave = tid >> 6;
    const int lane = tid & 63;
    const int quad = lane >> 4;
    const int l16  = lane & 15;

    const int mb    = blockIdx.y;
    const int gbase = blockIdx.x * BG;
    const int nbase = blockIdx.z * NCHUNK;

    const float LOG2E = 1.44269504088896340736f;
    const float inv0 = 1.0f / (1e-5f + log1pf(__expf(lsp[0])));
    const float inv1 = 1.0f / (1e-5f + log1pf(__expf(lsp[1])));

    // Two row-groups per wave: rows wave*32 + {l16, 16+l16}.
    float qxL[2], qyL[2], hq[2];
#pragma unroll
    for (int g = 0; g < 2; g++) {
        const int grow = gbase + wave * 32 + g * 16 + l16;
        const float2 qraw = *(const float2*)&x_grid[(size_t)(mb * G_TOT + grow) * 2];
        const float qx = qraw.x * inv0, qy = qraw.y * inv1;
        qxL[g] = LOG2E * qx;
        qyL[g] = LOG2E * qy;
        hq[g]  = -0.5f * LOG2E * (qx * qx + qy * qy);
    }

    // Staging: sdzg = dz-group (consecutive lanes -> consecutive dz -> coalesced
    // float4 global loads), snq = n-quad (n = snq*4 + j).
    const int sdzg = tid & 15;
    const int snq  = tid >> 4;
    const float* zb = z + (size_t)mb * N_TOT * DZ + sdzg * 4;
    // Swizzled write bases (loop-invariant). Row d = sdzg*4 + i; swz(d) = (d>>1)&7
    // = (sdzg&3)*2 + (i>>1). Logical block = snq>>1, sub-offset = (snq&1)*8.
    const unsigned wrow  = (unsigned)(sdzg * 4) * ZROW_B + (unsigned)(snq & 1) * 8;
    const unsigned wb_lo = (unsigned)(((snq >> 1) ^ ((sdzg & 3) * 2 + 0)) & 7) * 16;  // i = 0,1
    const unsigned wb_hi = (unsigned)(((snq >> 1) ^ ((sdzg & 3) * 2 + 1)) & 7) * 16;  // i = 2,3

    // Swizzled read bases: row r = nt*16 + l16 -> swz = (l16>>1)&7 (nt*8 ≡ 0 mod 8);
    // block b = kc*4 + quad -> phys = (quad ^ swz) ^ (kc*4).
    const unsigned swz_l = (unsigned)((l16 >> 1) & 7);
    const unsigned q0    = (unsigned)quad ^ swz_l;
    const unsigned rbA   = (unsigned)l16 * ZROW_B + q0 * 16;         // kc = 0
    const unsigned rbB   = (unsigned)l16 * ZROW_B + (q0 ^ 4u) * 16;  // kc = 1

    f32x4 acc[2][4];
#pragma unroll
    for (int g = 0; g < 2; g++)
#pragma unroll
        for (int i = 0; i < 4; i++) acc[g][i] = (f32x4){0.f, 0.f, 0.f, 0.f};

    auto stage = [&](unsigned dst, const float4* zf, float2 kraw) {
        const float a0[4] = {zf[0].x, zf[0].y, zf[0].z, zf[0].w};
        const float a1[4] = {zf[1].x, zf[1].y, zf[1].z, zf[1].w};
        const float a2[4] = {zf[2].x, zf[2].y, zf[2].z, zf[2].w};
        const float a3[4] = {zf[3].x, zf[3].y, zf[3].z, zf[3].w};
#pragma unroll
        for (int i = 0; i < 4; i++) {
            uint2 w;
            w.x = pack_bf16_pair(a0[i], a1[i]);
            w.y = pack_bf16_pair(a2[i], a3[i]);
            const unsigned base = (i < 2) ? wb_lo : wb_hi;
            *(uint2*)(lds + dst + wrow + i * ZROW_B + base) = w;
        }
        if (tid < BN) {
            const float kx = kraw.x * inv0, ky = kraw.y * inv1;
            *(float*)(lds + dst + KX_OFS + tid * 4) = kx;
            *(float*)(lds + dst + KY_OFS + tid * 4) = ky;
            *(float*)(lds + dst + HK_OFS + tid * 4) = -0.5f * LOG2E * (kx * kx + ky * ky);
        }
    };

    // ---- prologue: fetch + stage tile 0 into buffer 0 ----
    {
        float4 zf[4];
        float2 kraw = {0.f, 0.f};
        const float* zp = zb + (size_t)(nbase + snq * 4) * DZ;
#pragma unroll
        for (int j = 0; j < 4; j++) zf[j] = *(const float4*)(zp + j * DZ);
        if (tid < BN) kraw = *(const float2*)(x + (size_t)(mb * N_TOT + nbase + tid) * 2);
        stage(0u, zf, kraw);
    }
    __syncthreads();

    for (int t = 0; t < ITERS; t++) {
        const unsigned bo = (unsigned)((t & 1) ? BUF_B : 0);
        const unsigned bn = bo ^ (unsigned)BUF_B;

        // ---- issue next tile's global loads (latency hidden under compute) ----
        float4 zf[4];
        float2 kraw = {0.f, 0.f};
        if (t + 1 < ITERS) {
            const int nb1 = nbase + (t + 1) * BN;
            const float* zp = zb + (size_t)(nb1 + snq * 4) * DZ;
#pragma unroll
            for (int j = 0; j < 4; j++) zf[j] = *(const float4*)(zp + j * DZ);
            if (tid < BN) kraw = *(const float2*)(x + (size_t)(mb * N_TOT + nb1 + tid) * 2);
        }

        // ---- compute tile t from buffer bo ----
#pragma unroll
        for (int kc = 0; kc < 2; kc++) {
            const unsigned kb = bo + (unsigned)(kc * 128 + quad * 32);
            const float4 kxa = *(const float4*)(lds + kb + KX_OFS);
            const float4 kxb = *(const float4*)(lds + kb + KX_OFS + 16);
            const float4 kya = *(const float4*)(lds + kb + KY_OFS);
            const float4 kyb = *(const float4*)(lds + kb + KY_OFS + 16);
            const float4 hka = *(const float4*)(lds + kb + HK_OFS);
            const float4 hkb = *(const float4*)(lds + kb + HK_OFS + 16);
            const float kxr[8] = {kxa.x, kxa.y, kxa.z, kxa.w, kxb.x, kxb.y, kxb.z, kxb.w};
            const float kyr[8] = {kya.x, kya.y, kya.z, kya.w, kyb.x, kyb.y, kyb.z, kyb.w};
            const float hkr[8] = {hka.x, hka.y, hka.z, hka.w, hkb.x, hkb.y, hkb.z, hkb.w};

            // Weights for both row-groups, directly in A-frag layout.
            unsigned aw[2][4];
#pragma unroll
            for (int jp = 0; jp < 4; jp++) {
#pragma unroll
                for (int g = 0; g < 2; g++) {
                    const float s0 = fmaf(qxL[g], kxr[2 * jp],
                                      fmaf(qyL[g], kyr[2 * jp], hq[g] + hkr[2 * jp]));
                    const float s1 = fmaf(qxL[g], kxr[2 * jp + 1],
                                      fmaf(qyL[g], kyr[2 * jp + 1], hq[g] + hkr[2 * jp + 1]));
                    aw[g][jp] = pack_bf16_pair(__builtin_amdgcn_exp2f(s0),
                                               __builtin_amdgcn_exp2f(s1));
                }
            }
            const int4v  a0v = {(int)aw[0][0], (int)aw[0][1], (int)aw[0][2], (int)aw[0][3]};
            const int4v  a1v = {(int)aw[1][0], (int)aw[1][1], (int)aw[1][2], (int)aw[1][3]};
            const short8 af0 = __builtin_bit_cast(short8, a0v);
            const short8 af1 = __builtin_bit_cast(short8, a1v);

            // B-frags (shared by both row-groups) + 8 MFMA.
            const unsigned rb = bo + ((kc == 0) ? rbA : rbB);
#pragma unroll
            for (int nt = 0; nt < 4; nt++) {
                const short8 bfrag = *(const short8*)(lds + rb + nt * (16 * ZROW_B));
                acc[0][nt] = __builtin_amdgcn_mfma_f32_16x16x32_bf16(af0, bfrag, acc[0][nt], 0, 0, 0);
                acc[1][nt] = __builtin_amdgcn_mfma_f32_16x16x32_bf16(af1, bfrag, acc[1][nt], 0, 0, 0);
            }
        }

        // ---- stage next tile into buffer bn; single barrier per iteration ----
        if (t + 1 < ITERS) {
            stage(bn, zf, kraw);
            __syncthreads();
        }
    }

    // ---- epilogue: C/D layout col = lane&15 (dz), row = quad*4 + reg (g-row) ----
    // out was memset to 0; all 8 n-splits atomicAdd (RMW resolves at the
    // shared cache; placement-independent). Split 0 folds z_grid in.
    const bool add_zg = (blockIdx.z == 0);
#pragma unroll
    for (int g = 0; g < 2; g++) {
        const int gout = gbase + wave * 32 + g * 16 + quad * 4;
#pragma unroll
        for (int nt = 0; nt < 4; nt++) {
#pragma unroll
            for (int r = 0; r < 4; r++) {
                const size_t idx = (size_t)(mb * G_TOT + gout + r) * DZ + nt * 16 + l16;
                const float v = add_zg ? (acc[g][nt][r] + z_grid[idx]) : acc[g][nt][r];
                atomicAdd(&out[idx], v);
            }
        }
    }
}

extern "C" void kernel_launch(void* const* d_in, const int* in_sizes, int n_in,
                              void* d_out, int out_size, void* d_ws, size_t ws_size,
                              hipStream_t stream) {
    const float* x   = (const float*)d_in[0];
    const float* z   = (const float*)d_in[1];
    const float* xg  = (const float*)d_in[2];
    const float* zgr = (const float*)d_in[3];
    const float* lsp = (const float*)d_in[4];
    float* out = (float*)d_out;

    // out = 0 (write-only memset node; z_grid folded in by split 0's atomics)
    hipMemsetAsync(out, 0, sizeof(float) * (size_t)M_TOT * G_TOT * DZ, stream);

    dim3 grid(G_TOT / BG, M_TOT, NSPLIT);   // (128, 2, 8) = 2048 blocks
    setconv_kernel<<<grid, THREADS, 0, stream>>>(x, z, xg, zgr, lsp, out);
}

// Round 6
// 124.669 us; speedup vs baseline: 2.2282x; 1.0918x over previous
//
#include <hip/hip_runtime.h>
#include <hip/hip_bf16.h>
#include <math.h>

// Problem constants (fixed by setup_inputs)
#define M_TOT 2
#define N_TOT 4096
#define DZ    64
#define G_TOT 16384

// R5 post-mortem: spill fixed (VGPR 52, FETCH 12.7MB) but occupancy stayed
// ~34% with 2048 blocks -> residency is capped by the register-allocation
// quantum: 52 arch + 32 acc = 84 total rounds into a 128-reg slot -> 4
// waves/SIMD regardless of grid. Getting under the 64-slot needs <=32 arch
// regs (R1-R4: catastrophic spill). Occupancy axis exhausted.
// This round: revert to the proven 1024-block grid (R0: 57us, WRITE=32MB,
// FETCH=12.7MB) and cut per-wave critical path instead: v_pk_fma_f32 /
// v_pk_add_f32 packed-f32 weight math. Per weight-pair: 1 pk_add + 2 pk_fma
// (3 VALU) replaces 2 add + 4 fma (6 VALU), bit-identical fused ordering.
// ~24k cy/CU VALU removed; weight dependent chain 7 -> 5 ops.
#define BG      128
#define BN      64
#define THREADS 256
#define NSPLIT  4
#define NCHUNK  (N_TOT / NSPLIT)   // 1024
#define ITERS   (NCHUNK / BN)      // 16
// zT: bf16 [dz=64][n=64], row = 128 B. Full 3-bit XOR swizzle of the 16B block:
// phys_block = logical_block ^ ((row>>1)&7). Proven conflict-free for both the
// b64 staging writes (4 dwords/bank = b64 floor) and the b128 B-frag reads
// (8 dwords/bank = b128 floor). k-order inside 16B blocks preserved.
#define ZROW_B  128
#define ZT_B    (DZ * ZROW_B)      // 8192
#define KX_OFS  ZT_B               // 8192
#define KY_OFS  (KX_OFS + BN * 4)  // 8448
#define HK_OFS  (KY_OFS + BN * 4)  // 8704
#define BUF_B   (HK_OFS + BN * 4)  // 8960 bytes per pipeline buffer

typedef __attribute__((ext_vector_type(8))) short short8;  // 8 bf16 MFMA A/B frag
typedef __attribute__((ext_vector_type(4))) float f32x4;   // MFMA C/D frag
typedef __attribute__((ext_vector_type(2))) float f32x2;   // packed-f32 pair
typedef __attribute__((ext_vector_type(4))) int   int4v;

#if __has_builtin(__builtin_amdgcn_cvt_pk_bf16_f32)
typedef __attribute__((ext_vector_type(2))) __bf16 bf16x2;
__device__ __forceinline__ unsigned int pack_bf16_pair(float lo, float hi) {
    return __builtin_bit_cast(unsigned int, __builtin_amdgcn_cvt_pk_bf16_f32(lo, hi));
}
#else
__device__ __forceinline__ unsigned int pack_bf16_pair(float lo, float hi) {
    const unsigned int a = __float_as_uint(lo) + 0x8000u;  // round-half-up to bf16
    const unsigned int b = __float_as_uint(hi) + 0x8000u;
    return __builtin_amdgcn_perm(b, a, 0x07060302u);       // [lo[31:16], hi[31:16]]
}
#endif

// Packed f32 math (CDNA gfx90a+; 2x f32 FMA per instruction). Pure ops
// (no volatile) so the scheduler can move/CSE them freely.
__device__ __forceinline__ f32x2 pk_fma(f32x2 a, f32x2 b, f32x2 c) {
    f32x2 d;
    asm("v_pk_fma_f32 %0, %1, %2, %3" : "=v"(d) : "v"(a), "v"(b), "v"(c));
    return d;
}
__device__ __forceinline__ f32x2 pk_add(f32x2 a, f32x2 b) {
    f32x2 d;
    asm("v_pk_add_f32 %0, %1, %2" : "=v"(d) : "v"(a), "v"(b));
    return d;
}

__global__ __launch_bounds__(THREADS, 4)  // cap 128 regs: known-good (R0, no spill)
void setconv_kernel(const float* __restrict__ x,       // [2][4096][2]
                    const float* __restrict__ z,       // [2][4096][64]
                    const float* __restrict__ x_grid,  // [2][16384][2]
                    const float* __restrict__ z_grid,  // [2][16384][64]
                    const float* __restrict__ lsp,     // [2]
                    float* __restrict__ out)           // [2][16384][64], memset to 0
{
    __shared__ __align__(16) unsigned char lds[2 * BUF_B];

    const int tid  = threadIdx.x;
    const int wave = tid >> 6;
    const int lane = tid & 63;
    const int quad = lane >> 4;
    const int l16  = lane & 15;

    const int mb    = blockIdx.y;
    const int gbase = blockIdx.x * BG;
    const int nbase = blockIdx.z * NCHUNK;

    const float LOG2E = 1.44269504088896340736f;
    const float inv0 = 1.0f / (1e-5f + log1pf(__expf(lsp[0])));
    const float inv1 = 1.0f / (1e-5f + log1pf(__expf(lsp[1])));

    // Two row-groups per wave: rows wave*32 + {l16, 16+l16}. Broadcast pairs
    // for packed math (s computed for 2 consecutive k at once).
    f32x2 qxp[2], qyp[2], hqp[2];
#pragma unroll
    for (int g = 0; g < 2; g++) {
        const int grow = gbase + wave * 32 + g * 16 + l16;
        const float2 qraw = *(const float2*)&x_grid[(size_t)(mb * G_TOT + grow) * 2];
        const float qx = qraw.x * inv0, qy = qraw.y * inv1;
        const float qxL = LOG2E * qx;
        const float qyL = LOG2E * qy;
        const float hq  = -0.5f * LOG2E * (qx * qx + qy * qy);
        qxp[g] = (f32x2){qxL, qxL};
        qyp[g] = (f32x2){qyL, qyL};
        hqp[g] = (f32x2){hq, hq};
    }

    // Staging: sdzg = dz-group (consecutive lanes -> consecutive dz -> coalesced
    // float4 global loads), snq = n-quad (n = snq*4 + j).
    const int sdzg = tid & 15;
    const int snq  = tid >> 4;
    const float* zb = z + (size_t)mb * N_TOT * DZ + sdzg * 4;
    // Swizzled write bases (loop-invariant). Row d = sdzg*4 + i; swz(d) = (d>>1)&7
    // = (sdzg&3)*2 + (i>>1). Logical block = snq>>1, sub-offset = (snq&1)*8.
    const unsigned wrow  = (unsigned)(sdzg * 4) * ZROW_B + (unsigned)(snq & 1) * 8;
    const unsigned wb_lo = (unsigned)(((snq >> 1) ^ ((sdzg & 3) * 2 + 0)) & 7) * 16;  // i = 0,1
    const unsigned wb_hi = (unsigned)(((snq >> 1) ^ ((sdzg & 3) * 2 + 1)) & 7) * 16;  // i = 2,3

    // Swizzled read bases: row r = nt*16 + l16 -> swz = (l16>>1)&7 (nt*8 ≡ 0 mod 8);
    // block b = kc*4 + quad -> phys = (quad ^ swz) ^ (kc*4).
    const unsigned swz_l = (unsigned)((l16 >> 1) & 7);
    const unsigned q0    = (unsigned)quad ^ swz_l;
    const unsigned rbA   = (unsigned)l16 * ZROW_B + q0 * 16;         // kc = 0
    const unsigned rbB   = (unsigned)l16 * ZROW_B + (q0 ^ 4u) * 16;  // kc = 1

    f32x4 acc[2][4];
#pragma unroll
    for (int g = 0; g < 2; g++)
#pragma unroll
        for (int i = 0; i < 4; i++) acc[g][i] = (f32x4){0.f, 0.f, 0.f, 0.f};

    auto stage = [&](unsigned dst, const float4* zf, float2 kraw) {
        const float a0[4] = {zf[0].x, zf[0].y, zf[0].z, zf[0].w};
        const float a1[4] = {zf[1].x, zf[1].y, zf[1].z, zf[1].w};
        const float a2[4] = {zf[2].x, zf[2].y, zf[2].z, zf[2].w};
        const float a3[4] = {zf[3].x, zf[3].y, zf[3].z, zf[3].w};
#pragma unroll
        for (int i = 0; i < 4; i++) {
            uint2 w;
            w.x = pack_bf16_pair(a0[i], a1[i]);
            w.y = pack_bf16_pair(a2[i], a3[i]);
            const unsigned base = (i < 2) ? wb_lo : wb_hi;
            *(uint2*)(lds + dst + wrow + i * ZROW_B + base) = w;
        }
        if (tid < BN) {
            const float kx = kraw.x * inv0, ky = kraw.y * inv1;
            *(float*)(lds + dst + KX_OFS + tid * 4) = kx;
            *(float*)(lds + dst + KY_OFS + tid * 4) = ky;
            *(float*)(lds + dst + HK_OFS + tid * 4) = -0.5f * LOG2E * (kx * kx + ky * ky);
        }
    };

    // ---- prologue: fetch + stage tile 0 into buffer 0 ----
    {
        float4 zf[4];
        float2 kraw = {0.f, 0.f};
        const float* zp = zb + (size_t)(nbase + snq * 4) * DZ;
#pragma unroll
        for (int j = 0; j < 4; j++) zf[j] = *(const float4*)(zp + j * DZ);
        if (tid < BN) kraw = *(const float2*)(x + (size_t)(mb * N_TOT + nbase + tid) * 2);
        stage(0u, zf, kraw);
    }
    __syncthreads();

    for (int t = 0; t < ITERS; t++) {
        const unsigned bo = (unsigned)((t & 1) ? BUF_B : 0);
        const unsigned bn = bo ^ (unsigned)BUF_B;

        // ---- issue next tile's global loads (latency hidden under compute) ----
        float4 zf[4];
        float2 kraw = {0.f, 0.f};
        if (t + 1 < ITERS) {
            const int nb1 = nbase + (t + 1) * BN;
            const float* zp = zb + (size_t)(nb1 + snq * 4) * DZ;
#pragma unroll
            for (int j = 0; j < 4; j++) zf[j] = *(const float4*)(zp + j * DZ);
            if (tid < BN) kraw = *(const float2*)(x + (size_t)(mb * N_TOT + nb1 + tid) * 2);
        }

        // ---- compute tile t from buffer bo ----
#pragma unroll
        for (int kc = 0; kc < 2; kc++) {
            const unsigned kb = bo + (unsigned)(kc * 128 + quad * 32);
            // k-values as b64 pairs: clean even-aligned VGPR pairs for pk ops
            // (no extract moves). Quad-uniform addresses -> broadcast, no
            // bank conflicts.
            f32x2 kxp[4], kyp[4], hkp[4];
#pragma unroll
            for (int jp = 0; jp < 4; jp++) {
                kxp[jp] = *(const f32x2*)(lds + kb + KX_OFS + jp * 8);
                kyp[jp] = *(const f32x2*)(lds + kb + KY_OFS + jp * 8);
                hkp[jp] = *(const f32x2*)(lds + kb + HK_OFS + jp * 8);
            }

            // Weights for both row-groups, directly in A-frag layout.
            // s(pair) = qx*kx + (qy*ky + (hq + hk)) -- identical fused
            // ordering to the scalar version, 3 packed ops per weight-pair.
            unsigned aw[2][4];
#pragma unroll
            for (int jp = 0; jp < 4; jp++) {
#pragma unroll
                for (int g = 0; g < 2; g++) {
                    const f32x2 s = pk_fma(qxp[g], kxp[jp],
                                     pk_fma(qyp[g], kyp[jp],
                                      pk_add(hqp[g], hkp[jp])));
                    aw[g][jp] = pack_bf16_pair(__builtin_amdgcn_exp2f(s.x),
                                               __builtin_amdgcn_exp2f(s.y));
                }
            }
            const int4v  a0v = {(int)aw[0][0], (int)aw[0][1], (int)aw[0][2], (int)aw[0][3]};
            const int4v  a1v = {(int)aw[1][0], (int)aw[1][1], (int)aw[1][2], (int)aw[1][3]};
            const short8 af0 = __builtin_bit_cast(short8, a0v);
            const short8 af1 = __builtin_bit_cast(short8, a1v);

            // B-frags (shared by both row-groups) + 8 MFMA.
            const unsigned rb = bo + ((kc == 0) ? rbA : rbB);
#pragma unroll
            for (int nt = 0; nt < 4; nt++) {
                const short8 bfrag = *(const short8*)(lds + rb + nt * (16 * ZROW_B));
                acc[0][nt] = __builtin_amdgcn_mfma_f32_16x16x32_bf16(af0, bfrag, acc[0][nt], 0, 0, 0);
                acc[1][nt] = __builtin_amdgcn_mfma_f32_16x16x32_bf16(af1, bfrag, acc[1][nt], 0, 0, 0);
            }
        }

        // ---- stage next tile into buffer bn; single barrier per iteration ----
        if (t + 1 < ITERS) {
            stage(bn, zf, kraw);
            __syncthreads();
        }
    }

    // ---- epilogue: C/D layout col = lane&15 (dz), row = quad*4 + reg (g-row) ----
    // out was memset to 0; all 4 n-splits atomicAdd (RMW resolves at the
    // shared cache; R0-proven clean). Split 0 folds z_grid in.
    const bool add_zg = (blockIdx.z == 0);
#pragma unroll
    for (int g = 0; g < 2; g++) {
        const int gout = gbase + wave * 32 + g * 16 + quad * 4;
#pragma unroll
        for (int nt = 0; nt < 4; nt++) {
#pragma unroll
            for (int r = 0; r < 4; r++) {
                const size_t idx = (size_t)(mb * G_TOT + gout + r) * DZ + nt * 16 + l16;
                const float v = add_zg ? (acc[g][nt][r] + z_grid[idx]) : acc[g][nt][r];
                atomicAdd(&out[idx], v);
            }
        }
    }
}

extern "C" void kernel_launch(void* const* d_in, const int* in_sizes, int n_in,
                              void* d_out, int out_size, void* d_ws, size_t ws_size,
                              hipStream_t stream) {
    const float* x   = (const float*)d_in[0];
    const float* z   = (const float*)d_in[1];
    const float* xg  = (const float*)d_in[2];
    const float* zgr = (const float*)d_in[3];
    const float* lsp = (const float*)d_in[4];
    float* out = (float*)d_out;

    // out = 0 (write-only memset node; z_grid folded in by split 0's atomics)
    hipMemsetAsync(out, 0, sizeof(float) * (size_t)M_TOT * G_TOT * DZ, stream);

    dim3 grid(G_TOT / BG, M_TOT, NSPLIT);   // (128, 2, 4) = 1024 blocks
    setconv_kernel<<<grid, THREADS, 0, stream>>>(x, z, xg, zgr, lsp, out);
}

// Round 7
// 124.637 us; speedup vs baseline: 2.2287x; 1.0003x over previous
//
#include <hip/hip_runtime.h>
#include <hip/hip_bf16.h>
#include <math.h>

// Problem constants (fixed by setup_inputs)
#define M_TOT 2
#define N_TOT 4096
#define DZ    64
#define G_TOT 16384

// R6 post-mortem: removing VALU work left dur flat -> VALU not critical.
// Corrected budget: 16 waves/CU, 64 block-iterations/CU over ~137k cy =
// 2.1k cy/iteration; LDS instrs/iteration ~140 (~1.5k cy) -> LDS pipe ~70%
// saturated = the bottleneck. k-value broadcasts are 96/140 instrs (24 b64
// per wave-tile for 768 unique bytes).
// This round: cut k-read instrs 24 -> 8 per wave-tile:
//  (1) interleaved records {kx0,kx1,ky0,ky1} -> one ds_read_b128 per jp
//      yields both pk-aligned pairs;
//  (2) hk recomputed in-register: u = kx^2+ky^2 shared across row-groups
//      (2 pk ops/jp), HK array + its staging + 8 reads eliminated.
#define BG      128
#define BN      64
#define THREADS 256
#define NSPLIT  4
#define NCHUNK  (N_TOT / NSPLIT)   // 1024
#define ITERS   (NCHUNK / BN)      // 16
// zT: bf16 [dz=64][n=64], row = 128 B. Full 3-bit XOR swizzle of the 16B block:
// phys_block = logical_block ^ ((row>>1)&7). Proven conflict-free for both the
// b64 staging writes (4 dwords/bank = b64 floor) and the b128 B-frag reads
// (8 dwords/bank = b128 floor). k-order inside 16B blocks preserved.
// KP: 32 records x 16B = 512B: record j = {kx_2j, kx_2j+1, ky_2j, ky_2j+1}.
// Read per (kc,quad,jp): b128 at kc*256 + quad*64 + jp*16, quad-uniform
// broadcast; quads {0,2} and {1,3} alias banks 2-way = free (m136).
#define ZROW_B  128
#define ZT_B    (DZ * ZROW_B)      // 8192
#define KP_OFS  ZT_B               // 8192
#define BUF_B   (KP_OFS + BN * 8)  // 8704 bytes per pipeline buffer

typedef __attribute__((ext_vector_type(8))) short short8;  // 8 bf16 MFMA A/B frag
typedef __attribute__((ext_vector_type(4))) float f32x4;   // MFMA C/D frag
typedef __attribute__((ext_vector_type(2))) float f32x2;   // packed-f32 pair
typedef __attribute__((ext_vector_type(4))) int   int4v;

#if __has_builtin(__builtin_amdgcn_cvt_pk_bf16_f32)
typedef __attribute__((ext_vector_type(2))) __bf16 bf16x2;
__device__ __forceinline__ unsigned int pack_bf16_pair(float lo, float hi) {
    return __builtin_bit_cast(unsigned int, __builtin_amdgcn_cvt_pk_bf16_f32(lo, hi));
}
#else
__device__ __forceinline__ unsigned int pack_bf16_pair(float lo, float hi) {
    const unsigned int a = __float_as_uint(lo) + 0x8000u;  // round-half-up to bf16
    const unsigned int b = __float_as_uint(hi) + 0x8000u;
    return __builtin_amdgcn_perm(b, a, 0x07060302u);       // [lo[31:16], hi[31:16]]
}
#endif

// Packed f32 math (CDNA gfx90a+; 2x f32 per instruction). Pure ops (no
// volatile) so the scheduler can move/CSE them freely.
__device__ __forceinline__ f32x2 pk_fma(f32x2 a, f32x2 b, f32x2 c) {
    f32x2 d;
    asm("v_pk_fma_f32 %0, %1, %2, %3" : "=v"(d) : "v"(a), "v"(b), "v"(c));
    return d;
}
__device__ __forceinline__ f32x2 pk_mul(f32x2 a, f32x2 b) {
    f32x2 d;
    asm("v_pk_mul_f32 %0, %1, %2" : "=v"(d) : "v"(a), "v"(b));
    return d;
}

__global__ __launch_bounds__(THREADS, 4)  // cap 128 regs: known-good (no spill)
void setconv_kernel(const float* __restrict__ x,       // [2][4096][2]
                    const float* __restrict__ z,       // [2][4096][64]
                    const float* __restrict__ x_grid,  // [2][16384][2]
                    const float* __restrict__ z_grid,  // [2][16384][64]
                    const float* __restrict__ lsp,     // [2]
                    float* __restrict__ out)           // [2][16384][64], memset to 0
{
    __shared__ __align__(16) unsigned char lds[2 * BUF_B];

    const int tid  = threadIdx.x;
    const int wave = tid >> 6;
    const int lane = tid & 63;
    const int quad = lane >> 4;
    const int l16  = lane & 15;

    const int mb    = blockIdx.y;
    const int gbase = blockIdx.x * BG;
    const int nbase = blockIdx.z * NCHUNK;

    const float LOG2E = 1.44269504088896340736f;
    const float inv0 = 1.0f / (1e-5f + log1pf(__expf(lsp[0])));
    const float inv1 = 1.0f / (1e-5f + log1pf(__expf(lsp[1])));
    // hk = cL * (kx^2 + ky^2), cL = -0.5*LOG2E (kx,ky are ls-scaled coords)
    const f32x2 cL = (f32x2){-0.5f * LOG2E, -0.5f * LOG2E};

    // Two row-groups per wave: rows wave*32 + {l16, 16+l16}. Broadcast pairs
    // for packed math.
    f32x2 qxp[2], qyp[2], hqp[2];
#pragma unroll
    for (int g = 0; g < 2; g++) {
        const int grow = gbase + wave * 32 + g * 16 + l16;
        const float2 qraw = *(const float2*)&x_grid[(size_t)(mb * G_TOT + grow) * 2];
        const float qx = qraw.x * inv0, qy = qraw.y * inv1;
        const float qxL = LOG2E * qx;
        const float qyL = LOG2E * qy;
        const float hq  = -0.5f * LOG2E * (qx * qx + qy * qy);
        qxp[g] = (f32x2){qxL, qxL};
        qyp[g] = (f32x2){qyL, qyL};
        hqp[g] = (f32x2){hq, hq};
    }

    // Staging: sdzg = dz-group (consecutive lanes -> consecutive dz -> coalesced
    // float4 global loads), snq = n-quad (n = snq*4 + j).
    const int sdzg = tid & 15;
    const int snq  = tid >> 4;
    const float* zb = z + (size_t)mb * N_TOT * DZ + sdzg * 4;
    // Swizzled write bases (loop-invariant). Row d = sdzg*4 + i; swz(d) = (d>>1)&7
    // = (sdzg&3)*2 + (i>>1). Logical block = snq>>1, sub-offset = (snq&1)*8.
    const unsigned wrow  = (unsigned)(sdzg * 4) * ZROW_B + (unsigned)(snq & 1) * 8;
    const unsigned wb_lo = (unsigned)(((snq >> 1) ^ ((sdzg & 3) * 2 + 0)) & 7) * 16;  // i = 0,1
    const unsigned wb_hi = (unsigned)(((snq >> 1) ^ ((sdzg & 3) * 2 + 1)) & 7) * 16;  // i = 2,3

    // Swizzled read bases: row r = nt*16 + l16 -> swz = (l16>>1)&7 (nt*8 ≡ 0 mod 8);
    // block b = kc*4 + quad -> phys = (quad ^ swz) ^ (kc*4).
    const unsigned swz_l = (unsigned)((l16 >> 1) & 7);
    const unsigned q0    = (unsigned)quad ^ swz_l;
    const unsigned rbA   = (unsigned)l16 * ZROW_B + q0 * 16;         // kc = 0
    const unsigned rbB   = (unsigned)l16 * ZROW_B + (q0 ^ 4u) * 16;  // kc = 1
    // k-record base for this lane's quad (per kc add kc*256, per jp add jp*16)
    const unsigned kqb   = (unsigned)(KP_OFS + quad * 64);

    f32x4 acc[2][4];
#pragma unroll
    for (int g = 0; g < 2; g++)
#pragma unroll
        for (int i = 0; i < 4; i++) acc[g][i] = (f32x4){0.f, 0.f, 0.f, 0.f};

    auto stage = [&](unsigned dst, const float4* zf, float2 kraw) {
        const float a0[4] = {zf[0].x, zf[0].y, zf[0].z, zf[0].w};
        const float a1[4] = {zf[1].x, zf[1].y, zf[1].z, zf[1].w};
        const float a2[4] = {zf[2].x, zf[2].y, zf[2].z, zf[2].w};
        const float a3[4] = {zf[3].x, zf[3].y, zf[3].z, zf[3].w};
#pragma unroll
        for (int i = 0; i < 4; i++) {
            uint2 w;
            w.x = pack_bf16_pair(a0[i], a1[i]);
            w.y = pack_bf16_pair(a2[i], a3[i]);
            const unsigned base = (i < 2) ? wb_lo : wb_hi;
            *(uint2*)(lds + dst + wrow + i * ZROW_B + base) = w;
        }
        if (tid < BN) {
            // record j = n-pair: {kx_2j, kx_2j+1, ky_2j, ky_2j+1}
            const float kx = kraw.x * inv0, ky = kraw.y * inv1;
            const unsigned rb = dst + (unsigned)KP_OFS
                              + (unsigned)((tid >> 1) * 16 + (tid & 1) * 4);
            *(float*)(lds + rb)     = kx;
            *(float*)(lds + rb + 8) = ky;
        }
    };

    // ---- prologue: fetch + stage tile 0 into buffer 0 ----
    {
        float4 zf[4];
        float2 kraw = {0.f, 0.f};
        const float* zp = zb + (size_t)(nbase + snq * 4) * DZ;
#pragma unroll
        for (int j = 0; j < 4; j++) zf[j] = *(const float4*)(zp + j * DZ);
        if (tid < BN) kraw = *(const float2*)(x + (size_t)(mb * N_TOT + nbase + tid) * 2);
        stage(0u, zf, kraw);
    }
    __syncthreads();

    for (int t = 0; t < ITERS; t++) {
        const unsigned bo = (unsigned)((t & 1) ? BUF_B : 0);
        const unsigned bn = bo ^ (unsigned)BUF_B;

        // ---- issue next tile's global loads (latency hidden under compute) ----
        float4 zf[4];
        float2 kraw = {0.f, 0.f};
        if (t + 1 < ITERS) {
            const int nb1 = nbase + (t + 1) * BN;
            const float* zp = zb + (size_t)(nb1 + snq * 4) * DZ;
#pragma unroll
            for (int j = 0; j < 4; j++) zf[j] = *(const float4*)(zp + j * DZ);
            if (tid < BN) kraw = *(const float2*)(x + (size_t)(mb * N_TOT + nb1 + tid) * 2);
        }

        // ---- compute tile t from buffer bo ----
#pragma unroll
        for (int kc = 0; kc < 2; kc++) {
            // One b128 per jp: {kxp | kyp} pk-aligned pairs (broadcast read).
            unsigned aw[2][4];
#pragma unroll
            for (int jp = 0; jp < 4; jp++) {
                const f32x4 krec = *(const f32x4*)(lds + bo + kqb
                                                   + (unsigned)(kc * 256 + jp * 16));
                const f32x2 kxp = __builtin_shufflevector(krec, krec, 0, 1);
                const f32x2 kyp = __builtin_shufflevector(krec, krec, 2, 3);
                // u = kx^2 + ky^2, shared across both row-groups
                const f32x2 u = pk_fma(kxp, kxp, pk_mul(kyp, kyp));
#pragma unroll
                for (int g = 0; g < 2; g++) {
                    // s = qx*kx + (qy*ky + (cL*u + hq))  [== old hq+hk path]
                    const f32x2 s = pk_fma(qxp[g], kxp,
                                     pk_fma(qyp[g], kyp,
                                      pk_fma(u, cL, hqp[g])));
                    aw[g][jp] = pack_bf16_pair(__builtin_amdgcn_exp2f(s.x),
                                               __builtin_amdgcn_exp2f(s.y));
                }
            }
            const int4v  a0v = {(int)aw[0][0], (int)aw[0][1], (int)aw[0][2], (int)aw[0][3]};
            const int4v  a1v = {(int)aw[1][0], (int)aw[1][1], (int)aw[1][2], (int)aw[1][3]};
            const short8 af0 = __builtin_bit_cast(short8, a0v);
            const short8 af1 = __builtin_bit_cast(short8, a1v);

            // B-frags (shared by both row-groups) + 8 MFMA.
            const unsigned rb = bo + ((kc == 0) ? rbA : rbB);
#pragma unroll
            for (int nt = 0; nt < 4; nt++) {
                const short8 bfrag = *(const short8*)(lds + rb + nt * (16 * ZROW_B));
                acc[0][nt] = __builtin_amdgcn_mfma_f32_16x16x32_bf16(af0, bfrag, acc[0][nt], 0, 0, 0);
                acc[1][nt] = __builtin_amdgcn_mfma_f32_16x16x32_bf16(af1, bfrag, acc[1][nt], 0, 0, 0);
            }
        }

        // ---- stage next tile into buffer bn; single barrier per iteration ----
        if (t + 1 < ITERS) {
            stage(bn, zf, kraw);
            __syncthreads();
        }
    }

    // ---- epilogue: C/D layout col = lane&15 (dz), row = quad*4 + reg (g-row) ----
    // out was memset to 0; all 4 n-splits atomicAdd (RMW resolves at the
    // shared cache; R0-proven clean). Split 0 folds z_grid in.
    const bool add_zg = (blockIdx.z == 0);
#pragma unroll
    for (int g = 0; g < 2; g++) {
        const int gout = gbase + wave * 32 + g * 16 + quad * 4;
#pragma unroll
        for (int nt = 0; nt < 4; nt++) {
#pragma unroll
            for (int r = 0; r < 4; r++) {
                const size_t idx = (size_t)(mb * G_TOT + gout + r) * DZ + nt * 16 + l16;
                const float v = add_zg ? (acc[g][nt][r] + z_grid[idx]) : acc[g][nt][r];
                atomicAdd(&out[idx], v);
            }
        }
    }
}

extern "C" void kernel_launch(void* const* d_in, const int* in_sizes, int n_in,
                              void* d_out, int out_size, void* d_ws, size_t ws_size,
                              hipStream_t stream) {
    const float* x   = (const float*)d_in[0];
    const float* z   = (const float*)d_in[1];
    const float* xg  = (const float*)d_in[2];
    const float* zgr = (const float*)d_in[3];
    const float* lsp = (const float*)d_in[4];
    float* out = (float*)d_out;

    // out = 0 (write-only memset node; z_grid folded in by split 0's atomics)
    hipMemsetAsync(out, 0, sizeof(float) * (size_t)M_TOT * G_TOT * DZ, stream);

    dim3 grid(G_TOT / BG, M_TOT, NSPLIT);   // (128, 2, 4) = 1024 blocks
    setconv_kernel<<<grid, THREADS, 0, stream>>>(x, z, xg, zgr, lsp, out);
}

// Round 8
// 122.357 us; speedup vs baseline: 2.2703x; 1.0186x over previous
//
#include <hip/hip_runtime.h>
#include <hip/hip_bf16.h>
#include <math.h>

// Problem constants (fixed by setup_inputs)
#define M_TOT 2
#define N_TOT 4096
#define DZ    64
#define G_TOT 16384

// R7 post-mortem: VALU cut (R6) and LDS-instr cut (R7) both null -> no
// throughput pipe is the limit. 16 iterations take 137k cy = 8.5k/iter vs
// ~1k cy of per-wave content: per-iteration fixed overhead (barrier+drain,
// staging tail between drain and barrier, dependency ramp after barrier)
// dominates at 4 waves/SIMD. Fix: BN=128 -> 8 iterations, half the
// barriers/drains/tails, 2x independent work (4 kc-chunks, 32 MFMA) between
// barriers. Staging upgrades to 4x ds_write_b128/thread (each thread owns a
// full 16B n-block per dz row). LDS 34KB/block -> 4 blocks/CU kept.
#define BG      128
#define BN      128
#define THREADS 256
#define NSPLIT  4
#define NCHUNK  (N_TOT / NSPLIT)   // 1024
#define ITERS   (NCHUNK / BN)      // 8
// zT: bf16 [dz=64][n=128], row = 256 B = 16 x 16B blocks. 3-bit XOR swizzle
// of the block index: phys = logical ^ ((row>>1)&7) (bit 3 untouched).
// Conflict-free: staging b128 writes (8 lanes/bank-group x 4 dw = floor),
// B-frag b128 reads (8 dwords/bank = floor), k-record reads 2-way (free).
// KP: 64 records x 16B: record j = {kx_2j, kx_2j+1, ky_2j, ky_2j+1}.
#define ZROW_B  256
#define ZT_B    (DZ * ZROW_B)        // 16384
#define KP_OFS  ZT_B                 // 16384
#define BUF_B   (KP_OFS + (BN/2)*16) // 17408 bytes per pipeline buffer

typedef __attribute__((ext_vector_type(8))) short short8;  // 8 bf16 MFMA A/B frag
typedef __attribute__((ext_vector_type(4))) float f32x4;   // MFMA C/D frag
typedef __attribute__((ext_vector_type(2))) float f32x2;   // packed-f32 pair
typedef __attribute__((ext_vector_type(4))) int   int4v;

#if __has_builtin(__builtin_amdgcn_cvt_pk_bf16_f32)
typedef __attribute__((ext_vector_type(2))) __bf16 bf16x2;
__device__ __forceinline__ unsigned int pack_bf16_pair(float lo, float hi) {
    return __builtin_bit_cast(unsigned int, __builtin_amdgcn_cvt_pk_bf16_f32(lo, hi));
}
#else
__device__ __forceinline__ unsigned int pack_bf16_pair(float lo, float hi) {
    const unsigned int a = __float_as_uint(lo) + 0x8000u;  // round-half-up to bf16
    const unsigned int b = __float_as_uint(hi) + 0x8000u;
    return __builtin_amdgcn_perm(b, a, 0x07060302u);       // [lo[31:16], hi[31:16]]
}
#endif

// Packed f32 math (CDNA; 2x f32 per instruction).
__device__ __forceinline__ f32x2 pk_fma(f32x2 a, f32x2 b, f32x2 c) {
    f32x2 d;
    asm("v_pk_fma_f32 %0, %1, %2, %3" : "=v"(d) : "v"(a), "v"(b), "v"(c));
    return d;
}
__device__ __forceinline__ f32x2 pk_mul(f32x2 a, f32x2 b) {
    f32x2 d;
    asm("v_pk_mul_f32 %0, %1, %2" : "=v"(d) : "v"(a), "v"(b));
    return d;
}

__global__ __launch_bounds__(THREADS, 4)  // cap 128 regs: known-good (no spill)
void setconv_kernel(const float* __restrict__ x,       // [2][4096][2]
                    const float* __restrict__ z,       // [2][4096][64]
                    const float* __restrict__ x_grid,  // [2][16384][2]
                    const float* __restrict__ z_grid,  // [2][16384][64]
                    const float* __restrict__ lsp,     // [2]
                    float* __restrict__ out)           // [2][16384][64], memset to 0
{
    __shared__ __align__(16) unsigned char lds[2 * BUF_B];

    const int tid  = threadIdx.x;
    const int wave = tid >> 6;
    const int lane = tid & 63;
    const int quad = lane >> 4;
    const int l16  = lane & 15;

    const int mb    = blockIdx.y;
    const int gbase = blockIdx.x * BG;
    const int nbase = blockIdx.z * NCHUNK;

    const float LOG2E = 1.44269504088896340736f;
    const float inv0 = 1.0f / (1e-5f + log1pf(__expf(lsp[0])));
    const float inv1 = 1.0f / (1e-5f + log1pf(__expf(lsp[1])));
    const f32x2 cL = (f32x2){-0.5f * LOG2E, -0.5f * LOG2E};  // hk = cL*(kx^2+ky^2)

    // Two row-groups per wave: rows wave*32 + {l16, 16+l16}.
    f32x2 qxp[2], qyp[2], hqp[2];
#pragma unroll
    for (int g = 0; g < 2; g++) {
        const int grow = gbase + wave * 32 + g * 16 + l16;
        const float2 qraw = *(const float2*)&x_grid[(size_t)(mb * G_TOT + grow) * 2];
        const float qx = qraw.x * inv0, qy = qraw.y * inv1;
        const float qxL = LOG2E * qx;
        const float qyL = LOG2E * qy;
        const float hq  = -0.5f * LOG2E * (qx * qx + qy * qy);
        qxp[g] = (f32x2){qxL, qxL};
        qyp[g] = (f32x2){qyL, qyL};
        hqp[g] = (f32x2){hq, hq};
    }

    // Staging map (tile = 128n x 64dz): sdzg = tid&15 -> dz quad (coalesced
    // float4 global loads), snq = tid>>4 in [0,16) -> n-octet, n = snq*8+j.
    // Each thread owns a full 16B block (8 bf16) per dz row -> 4 b128 writes.
    // phys block = snq ^ ((row>>1)&7); row = sdzg*4+i -> swz = (2*sdzg+(i>>1))&7.
    const int sdzg = tid & 15;
    const int snq  = tid >> 4;
    const float* zb = z + (size_t)mb * N_TOT * DZ + sdzg * 4;

    // Swizzled B-frag read bases: row = nt*16+l16 -> swz = (l16>>1)&7;
    // block = kc*4+quad -> phys = (kc*4+quad) ^ swz (bit 3 passes through).
    const unsigned swz_l = (unsigned)((l16 >> 1) & 7);
    // k-record base for this lane's quad (add kc*256 + jp*16)
    const unsigned kqb   = (unsigned)(KP_OFS + quad * 64);

    f32x4 acc[2][4];
#pragma unroll
    for (int g = 0; g < 2; g++)
#pragma unroll
        for (int i = 0; i < 4; i++) acc[g][i] = (f32x4){0.f, 0.f, 0.f, 0.f};

    auto stage = [&](unsigned dst, const float4* zf, float2 kraw) {
        // m[i][j] = z[n=snq*8+j][dz=sdzg*4+i]
        const float m[4][8] = {
            {zf[0].x, zf[1].x, zf[2].x, zf[3].x, zf[4].x, zf[5].x, zf[6].x, zf[7].x},
            {zf[0].y, zf[1].y, zf[2].y, zf[3].y, zf[4].y, zf[5].y, zf[6].y, zf[7].y},
            {zf[0].z, zf[1].z, zf[2].z, zf[3].z, zf[4].z, zf[5].z, zf[6].z, zf[7].z},
            {zf[0].w, zf[1].w, zf[2].w, zf[3].w, zf[4].w, zf[5].w, zf[6].w, zf[7].w}};
#pragma unroll
        for (int i = 0; i < 4; i++) {
            int4v w;
            w.x = (int)pack_bf16_pair(m[i][0], m[i][1]);
            w.y = (int)pack_bf16_pair(m[i][2], m[i][3]);
            w.z = (int)pack_bf16_pair(m[i][4], m[i][5]);
            w.w = (int)pack_bf16_pair(m[i][6], m[i][7]);
            const unsigned phys = (unsigned)(snq ^ ((2 * sdzg + (i >> 1)) & 7));
            *(int4v*)(lds + dst + (unsigned)(sdzg * 4 + i) * ZROW_B + phys * 16) = w;
        }
        if (tid < BN) {
            // record j = n-pair: {kx_2j, kx_2j+1, ky_2j, ky_2j+1}
            const float kx = kraw.x * inv0, ky = kraw.y * inv1;
            const unsigned rb = dst + (unsigned)KP_OFS
                              + (unsigned)((tid >> 1) * 16 + (tid & 1) * 4);
            *(float*)(lds + rb)     = kx;
            *(float*)(lds + rb + 8) = ky;
        }
    };

    // ---- prologue: fetch + stage tile 0 into buffer 0 ----
    {
        float4 zf[8];
        float2 kraw = {0.f, 0.f};
        const float* zp = zb + (size_t)(nbase + snq * 8) * DZ;
#pragma unroll
        for (int j = 0; j < 8; j++) zf[j] = *(const float4*)(zp + j * DZ);
        if (tid < BN) kraw = *(const float2*)(x + (size_t)(mb * N_TOT + nbase + tid) * 2);
        stage(0u, zf, kraw);
    }
    __syncthreads();

    for (int t = 0; t < ITERS; t++) {
        const unsigned bo = (unsigned)((t & 1) ? BUF_B : 0);
        const unsigned bn = bo ^ (unsigned)BUF_B;

        // ---- issue next tile's global loads (latency hidden under compute) ----
        float4 zf[8];
        float2 kraw = {0.f, 0.f};
        if (t + 1 < ITERS) {
            const int nb1 = nbase + (t + 1) * BN;
            const float* zp = zb + (size_t)(nb1 + snq * 8) * DZ;
#pragma unroll
            for (int j = 0; j < 8; j++) zf[j] = *(const float4*)(zp + j * DZ);
            if (tid < BN) kraw = *(const float2*)(x + (size_t)(mb * N_TOT + nb1 + tid) * 2);
        }

        // ---- compute tile t from buffer bo: 4 kc-chunks of 32 n ----
#pragma unroll
        for (int kc = 0; kc < 4; kc++) {
            // One b128 per jp: {kxp | kyp} pk-aligned pairs (broadcast read).
            unsigned aw[2][4];
#pragma unroll
            for (int jp = 0; jp < 4; jp++) {
                const f32x4 krec = *(const f32x4*)(lds + bo + kqb
                                                   + (unsigned)(kc * 256 + jp * 16));
                const f32x2 kxp = __builtin_shufflevector(krec, krec, 0, 1);
                const f32x2 kyp = __builtin_shufflevector(krec, krec, 2, 3);
                const f32x2 u = pk_fma(kxp, kxp, pk_mul(kyp, kyp));  // kx^2+ky^2
#pragma unroll
                for (int g = 0; g < 2; g++) {
                    // s = qx*kx + (qy*ky + (cL*u + hq))
                    const f32x2 s = pk_fma(qxp[g], kxp,
                                     pk_fma(qyp[g], kyp,
                                      pk_fma(u, cL, hqp[g])));
                    aw[g][jp] = pack_bf16_pair(__builtin_amdgcn_exp2f(s.x),
                                               __builtin_amdgcn_exp2f(s.y));
                }
            }
            const int4v  a0v = {(int)aw[0][0], (int)aw[0][1], (int)aw[0][2], (int)aw[0][3]};
            const int4v  a1v = {(int)aw[1][0], (int)aw[1][1], (int)aw[1][2], (int)aw[1][3]};
            const short8 af0 = __builtin_bit_cast(short8, a0v);
            const short8 af1 = __builtin_bit_cast(short8, a1v);

            // B-frags (shared by both row-groups) + 8 MFMA.
            const unsigned rb = bo + (unsigned)l16 * ZROW_B
                              + (unsigned)(((kc * 4 + quad) ^ swz_l) * 16);
#pragma unroll
            for (int nt = 0; nt < 4; nt++) {
                const short8 bfrag = *(const short8*)(lds + rb + nt * (16 * ZROW_B));
                acc[0][nt] = __builtin_amdgcn_mfma_f32_16x16x32_bf16(af0, bfrag, acc[0][nt], 0, 0, 0);
                acc[1][nt] = __builtin_amdgcn_mfma_f32_16x16x32_bf16(af1, bfrag, acc[1][nt], 0, 0, 0);
            }
        }

        // ---- stage next tile into buffer bn; single barrier per iteration ----
        if (t + 1 < ITERS) {
            stage(bn, zf, kraw);
            __syncthreads();
        }
    }

    // ---- epilogue: C/D layout col = lane&15 (dz), row = quad*4 + reg (g-row) ----
    // out was memset to 0; all 4 n-splits atomicAdd (RMW resolves at the
    // shared cache; R0-proven clean). Split 0 folds z_grid in.
    const bool add_zg = (blockIdx.z == 0);
#pragma unroll
    for (int g = 0; g < 2; g++) {
        const int gout = gbase + wave * 32 + g * 16 + quad * 4;
#pragma unroll
        for (int nt = 0; nt < 4; nt++) {
#pragma unroll
            for (int r = 0; r < 4; r++) {
                const size_t idx = (size_t)(mb * G_TOT + gout + r) * DZ + nt * 16 + l16;
                const float v = add_zg ? (acc[g][nt][r] + z_grid[idx]) : acc[g][nt][r];
                atomicAdd(&out[idx], v);
            }
        }
    }
}

extern "C" void kernel_launch(void* const* d_in, const int* in_sizes, int n_in,
                              void* d_out, int out_size, void* d_ws, size_t ws_size,
                              hipStream_t stream) {
    const float* x   = (const float*)d_in[0];
    const float* z   = (const float*)d_in[1];
    const float* xg  = (const float*)d_in[2];
    const float* zgr = (const float*)d_in[3];
    const float* lsp = (const float*)d_in[4];
    float* out = (float*)d_out;

    // out = 0 (write-only memset node; z_grid folded in by split 0's atomics)
    hipMemsetAsync(out, 0, sizeof(float) * (size_t)M_TOT * G_TOT * DZ, stream);

    dim3 grid(G_TOT / BG, M_TOT, NSPLIT);   // (128, 2, 4) = 1024 blocks
    setconv_kernel<<<grid, THREADS, 0, stream>>>(x, z, xg, zgr, lsp, out);
}